// Round 7
// baseline (375.037 us; speedup 1.0000x reference)
//
#include <hip/hip_runtime.h>
#include <hip/hip_cooperative_groups.h>
#include <math.h>

namespace cg = cooperative_groups;

typedef unsigned int uint;
typedef unsigned short ushort;

typedef __attribute__((ext_vector_type(8))) _Float16 f16x8;
typedef __attribute__((ext_vector_type(2))) _Float16 f16x2;
typedef __attribute__((ext_vector_type(16))) float floatx16;

#define NFEAT 327680   // 256*1280 feats (f16)
#define NWA   163840   // W add-part, row-major [128][1280] (f16)
#define NWP   327680   // W diff/had part, fragment-packed (f16)
// ws: fH | wA | wP | stats f32[16] | Aoi f32[128*256]

union U4H8 { uint4 u; f16x8 h; uint w[4]; };

__device__ inline ushort f2h(float f) {
  _Float16 h = (_Float16)f;          // v_cvt_f16_f32, RNE
  union { _Float16 h; ushort s; } c; c.h = h; return c.s;
}
__device__ inline f16x2 asf16x2(uint u) {
  union { uint u; f16x2 h; } c; c.u = u; return c.h;
}
__device__ inline uint asuint(f16x2 h) {
  union { f16x2 h; uint u; } c; c.h = h; return c.u;
}

// ---------------- prep: fp32 -> fp16; W diff/had part packed into MFMA
// A-fragment order. Tile (ks 0..79, t 0..1, ob 0..3) = 512 ushorts:
// lane(0..63) = khalf*32 + (o&31) holds W[o][1280 + t*1280 + ks*16 + khalf*8 + 0..7].
__global__ void prep_kernel(const float* __restrict__ feats,
                            const float* __restrict__ W,
                            ushort* __restrict__ fH,
                            ushort* __restrict__ wA,
                            ushort* __restrict__ wP,
                            float* __restrict__ stats,
                            float* __restrict__ Aoi) {
  int idx = blockIdx.x * 256 + threadIdx.x;   // 3200*256 = NFEAT+NWA+NWP
  if (blockIdx.x == 0 && threadIdx.x < 16) stats[threadIdx.x] = 0.0f;
  if (idx < 32768) Aoi[idx] = 0.0f;
  if (idx < NFEAT) {
    fH[idx] = f2h(feats[idx]);
  } else {
    const int e = idx - NFEAT;
    const int o = e / 3840;
    const int c = e - o * 3840;
    const ushort v = f2h(W[e]);
    if (c < 1280) {
      wA[o * 1280 + c] = v;
    } else {
      const int cp = c - 1280;
      const int t = cp / 1280;            // 0=diff, 1=had
      const int kk = cp - t * 1280;
      const int ks = kk >> 4;
      const int khalf = (kk >> 3) & 1;
      const int ko = kk & 7;
      const int lane = khalf * 32 + (o & 31);
      const int tile = (ks * 2 + t) * 4 + (o >> 5);
      wP[tile * 512 + lane * 8 + ko] = v;
    }
  }
}

// ---------------- A[o,i] = sum_c Wa[o,c]*f[i,c] ----------------
// grid 128: 8 i-tiles x 4 kq x 4 ot
__global__ __launch_bounds__(256, 2) void gemma_kernel(
    const ushort* __restrict__ fH, const ushort* __restrict__ wA,
    float* __restrict__ Aoi) {
  __shared__ float red[4][1024];
  const int tid = threadIdx.x, lane = tid & 63, w = tid >> 6;
  const int i0 = (blockIdx.x >> 4) << 5;
  const int kq = (blockIdx.x >> 2) & 3;
  const int ot = blockIdx.x & 3;
  const int rr = lane & 31, half = lane >> 5;
  floatx16 a4;
  #pragma unroll
  for (int r = 0; r < 16; ++r) a4[r] = 0.0f;
  const int kbase = kq * 320 + w * 80 + half * 8;
  #pragma unroll
  for (int ks = 0; ks < 5; ++ks) {
    const int k = kbase + ks * 16;
    U4H8 bf; bf.u = *(const uint4*)(fH + (i0 + rr) * 1280 + k);
    U4H8 af; af.u = *(const uint4*)(wA + (ot * 32 + rr) * 1280 + k);
    a4 = __builtin_amdgcn_mfma_f32_32x32x16_f16(af.h, bf.h, a4, 0, 0, 0);
  }
  #pragma unroll
  for (int r = 0; r < 16; ++r) {
    const int orow = (r & 3) + 8 * (r >> 2) + 4 * half;
    red[w][orow * 32 + rr] = a4[r];
  }
  __syncthreads();
  for (int e = tid; e < 1024; e += 256) {
    float s = red[0][e] + red[1][e] + red[2][e] + red[3][e];
    atomicAdd(&Aoi[(ot * 32 + (e >> 5)) * 256 + i0 + (e & 31)], s);
  }
}

// build diff/had B-fragments: packed f16, no unpack/repack.
__device__ inline void build_pair(const uint4 vj, const uint4 vi, U4H8& d, U4H8& h) {
  const uint ju[4] = {vj.x, vj.y, vj.z, vj.w};
  const uint iu[4] = {vi.x, vi.y, vi.z, vi.w};
  #pragma unroll
  for (int t = 0; t < 4; ++t) {
    f16x2 a = asf16x2(iu[t]);
    f16x2 b = asf16x2(ju[t]);
    f16x2 dd = a - b;
    f16x2 hh = a * b;
    d.w[t] = asuint(dd) & 0x7fff7fffu;   // |a-b| (clear both sign bits)
    h.w[t] = asuint(hh);
  }
}

// ---------------- main fused GEMM + groupnorm + gelu ----------------
// R12: (a) occupancy: 512-thread blocks, 8 waves = 2 i-pairs x 2 o-halves
// x 2 j-stripes; each wave identical to R5's (2i x 64o x 32j, 16 MFMA per
// chunk, 14 loads). Grid 256 -> 2 blocks/CU -> 4 waves/SIMD (was 2).
// (b) fusion: keep x in acc, atomicAdd group stats, cooperative grid
// sync, normalize + exact GELU in-register, single write of out.
// Co-residency: 256 blocks <= 1 block/CU worst-case -> coop-safe.
__global__ __launch_bounds__(512, 4) void gemm_kernel(
    const ushort* __restrict__ fH, const ushort* __restrict__ wP,
    const float* __restrict__ bias, const float* __restrict__ Aoi,
    float* __restrict__ xout, float* __restrict__ stats,
    const float* __restrict__ gamma, const float* __restrict__ beta) {
  __shared__ float sred[16];

  const int tid = threadIdx.x;
  const int blk = blockIdx.x;          // 256 = 64 i-quads * 4 j-blocks
  const int i0 = (blk >> 2) << 2;      // first of 4 i-rows
  const int j0 = (blk & 3) << 6;
  const int lane = tid & 63;
  const int w = tid >> 6;              // 0..7
  const int p  = w >> 2;               // i-pair within quad
  const int ob = (w >> 1) & 1;         // o-half
  const int jb = w & 1;                // j-stripe
  const int wo = ob << 6;
  const int wm = jb << 5;
  const int rr = lane & 31;
  const int half = lane >> 5;

  // per-lane W-fragment base: ob tiles {2ob,2ob+1}; lane*8 ushorts
  const ushort* wpl = wP + ((wo >> 5) << 9) + lane * 8;
  const ushort* fi0p = fH + (i0 + p * 2) * 1280 + half * 8;
  const ushort* fi1p = fi0p + 1280;
  const ushort* fjp  = fH + (j0 + wm + rr) * 1280 + half * 8;

  floatx16 acc[2][2];   // [i][ot]
  #pragma unroll
  for (int a = 0; a < 2; ++a)
    #pragma unroll
    for (int ot = 0; ot < 2; ++ot)
      #pragma unroll
      for (int r = 0; r < 16; ++r) acc[a][ot][r] = 0.0f;

  U4H8 wfA[8], wfB[8];
  uint4 vjA[2], viA0[2], viA1[2], vjB[2], viB0[2], viB1[2];

  // frag index q = st*4 + t*2 + oi; tile = cc*16 + st*8 + t*4 + oi
#define CHUNK_LOAD(WF, VJ, VI0, VI1, CC) do {                                 \
    const int _b = (CC) * 16;                                                 \
    _Pragma("unroll")                                                         \
    for (int _q = 0; _q < 8; ++_q) {                                          \
      const int _st = _q >> 2, _t = (_q >> 1) & 1, _oi = _q & 1;              \
      (WF)[_q].u = *(const uint4*)(wpl + ((_b + _st * 8 + _t * 4 + _oi) << 9)); \
    }                                                                         \
    const int _cb = (CC) << 5;                                                \
    _Pragma("unroll")                                                         \
    for (int _s = 0; _s < 2; ++_s) {                                          \
      (VJ)[_s]  = *(const uint4*)(fjp  + _cb + _s * 16);                      \
      (VI0)[_s] = *(const uint4*)(fi0p + _cb + _s * 16);                      \
      (VI1)[_s] = *(const uint4*)(fi1p + _cb + _s * 16);                      \
    }                                                                         \
  } while (0)

#define CHUNK_COMPUTE(WF, VJ, VI0, VI1) do {                                  \
    _Pragma("unroll")                                                         \
    for (int _s = 0; _s < 2; ++_s) {                                          \
      U4H8 d0, h0, d1, h1;                                                    \
      build_pair((VJ)[_s], (VI0)[_s], d0, h0);                                \
      build_pair((VJ)[_s], (VI1)[_s], d1, h1);                                \
      acc[0][0] = __builtin_amdgcn_mfma_f32_32x32x16_f16((WF)[_s*4+0].h, d0.h, acc[0][0], 0, 0, 0); \
      acc[1][0] = __builtin_amdgcn_mfma_f32_32x32x16_f16((WF)[_s*4+0].h, d1.h, acc[1][0], 0, 0, 0); \
      acc[0][1] = __builtin_amdgcn_mfma_f32_32x32x16_f16((WF)[_s*4+1].h, d0.h, acc[0][1], 0, 0, 0); \
      acc[1][1] = __builtin_amdgcn_mfma_f32_32x32x16_f16((WF)[_s*4+1].h, d1.h, acc[1][1], 0, 0, 0); \
      acc[0][0] = __builtin_amdgcn_mfma_f32_32x32x16_f16((WF)[_s*4+2].h, h0.h, acc[0][0], 0, 0, 0); \
      acc[1][0] = __builtin_amdgcn_mfma_f32_32x32x16_f16((WF)[_s*4+2].h, h1.h, acc[1][0], 0, 0, 0); \
      acc[0][1] = __builtin_amdgcn_mfma_f32_32x32x16_f16((WF)[_s*4+3].h, h0.h, acc[0][1], 0, 0, 0); \
      acc[1][1] = __builtin_amdgcn_mfma_f32_32x32x16_f16((WF)[_s*4+3].h, h1.h, acc[1][1], 0, 0, 0); \
    }                                                                         \
  } while (0)

  CHUNK_LOAD(wfA, vjA, viA0, viA1, 0);
  #pragma unroll 1
  for (int cc = 0; cc < 40; cc += 2) {
    CHUNK_LOAD(wfB, vjB, viB0, viB1, cc + 1);     // prefetch odd chunk
    CHUNK_COMPUTE(wfA, vjA, viA0, viA1);          // compute even chunk
    if (cc + 2 < 40)
      CHUNK_LOAD(wfA, vjA, viA0, viA1, cc + 2);   // prefetch next even
    CHUNK_COMPUTE(wfB, vjB, viB0, viB1);          // compute odd chunk
  }
#undef CHUNK_LOAD
#undef CHUNK_COMPUTE

  // epilogue 1: x = acc + A[o,i]+A[o,j]+b[o] (kept in acc); group stats
  float gs[2][2] = {{0.f, 0.f}, {0.f, 0.f}};
  float gq[2][2] = {{0.f, 0.f}, {0.f, 0.f}};
  const int jg = j0 + wm + rr;
  #pragma unroll
  for (int ii = 0; ii < 2; ++ii) {
    const int irow = i0 + p * 2 + ii;
    #pragma unroll
    for (int ot = 0; ot < 2; ++ot) {
      #pragma unroll
      for (int r = 0; r < 16; ++r) {
        const int orow = (r & 3) + 8 * (r >> 2) + 4 * half;  // D row map (m74/m101)
        const int o = wo + ot * 32 + orow;
        float x = acc[ii][ot][r] + Aoi[o * 256 + irow] + Aoi[o * 256 + jg] + bias[o];
        acc[ii][ot][r] = x;
        gs[ot][r >> 3] += x;
        gq[ot][r >> 3] += x * x;
      }
    }
  }
  if (tid < 16) sred[tid] = 0.0f;
  __syncthreads();
  #pragma unroll
  for (int ot = 0; ot < 2; ++ot) {
    #pragma unroll
    for (int rg = 0; rg < 2; ++rg) {
      float s = gs[ot][rg], qv = gq[ot][rg];
      for (int off = 32; off > 0; off >>= 1) {
        s += __shfl_xor(s, off, 64);
        qv += __shfl_xor(qv, off, 64);
      }
      if (lane == 0) {
        const int g = (wo >> 4) + ot * 2 + rg;
        atomicAdd(&sred[g], s);
        atomicAdd(&sred[8 + g], qv);
      }
    }
  }
  __syncthreads();
  if (tid < 16) atomicAdd(&stats[tid], sred[tid]);

  // grid-wide: wait for all blocks' stats
  cg::this_grid().sync();

  // epilogue 2: groupnorm + exact gelu from registers, single store
  const float invN = 1.0f / 1048576.0f;  // 16*65536 per group
  float gmean[2][2], ginv[2][2];
  #pragma unroll
  for (int ot = 0; ot < 2; ++ot)
    #pragma unroll
    for (int rg = 0; rg < 2; ++rg) {
      const int g = (wo >> 4) + ot * 2 + rg;
      const float mean = stats[g] * invN;
      const float var = stats[8 + g] * invN - mean * mean;
      gmean[ot][rg] = mean;
      ginv[ot][rg] = rsqrtf(var + 1e-5f);
    }
  #pragma unroll
  for (int ii = 0; ii < 2; ++ii) {
    const int irow = i0 + p * 2 + ii;
    const int mglob = irow * 256 + jg;
    #pragma unroll
    for (int ot = 0; ot < 2; ++ot) {
      #pragma unroll
      for (int r = 0; r < 16; ++r) {
        const int orow = (r & 3) + 8 * (r >> 2) + 4 * half;
        const int o = wo + ot * 32 + orow;
        float xn = (acc[ii][ot][r] - gmean[ot][r >> 3]) * ginv[ot][r >> 3] * gamma[o] + beta[o];
        xout[o * 65536 + mglob] =
            0.5f * xn * (1.0f + erff(xn * 0.70710678118654752f));
      }
    }
  }
}

extern "C" void kernel_launch(void* const* d_in, const int* in_sizes, int n_in,
                              void* d_out, int out_size, void* d_ws, size_t ws_size,
                              hipStream_t stream) {
  const float* feats = (const float*)d_in[0];
  const float* W     = (const float*)d_in[1];
  const float* bias  = (const float*)d_in[2];
  const float* gamma = (const float*)d_in[3];
  const float* beta  = (const float*)d_in[4];
  float* out = (float*)d_out;

  ushort* fH = (ushort*)d_ws;
  ushort* wA = fH + NFEAT;
  ushort* wP = wA + NWA;
  float* stats = (float*)(wP + NWP);
  float* Aoi = stats + 16;

  prep_kernel<<<3200, 256, 0, stream>>>(feats, W, fH, wA, wP, stats, Aoi);
  gemma_kernel<<<128, 256, 0, stream>>>(fH, wA, Aoi);

  void* args[] = {&fH, &wP, &bias, &Aoi, &out, &stats, &gamma, &beta};
  hipLaunchCooperativeKernel((void*)gemm_kernel, dim3(256), dim3(512),
                             args, 0, stream);
}

// Round 8
// 146.631 us; speedup vs baseline: 2.5577x; 2.5577x over previous
//
#include <hip/hip_runtime.h>
#include <math.h>

typedef unsigned int uint;
typedef unsigned short ushort;

typedef __attribute__((ext_vector_type(8))) _Float16 f16x8;
typedef __attribute__((ext_vector_type(2))) _Float16 f16x2;
typedef __attribute__((ext_vector_type(16))) float floatx16;

#define NFEAT 327680   // 256*1280 feats (f16)
#define NWA   163840   // W add-part, row-major [128][1280] (f16)
#define NWP   327680   // W diff/had part, fragment-packed (f16)
// ws: fH | wA | wP | stats f32[16] | Aoi f32[128*256]

union U4H8 { uint4 u; f16x8 h; uint w[4]; };

__device__ inline ushort f2h(float f) {
  _Float16 h = (_Float16)f;          // v_cvt_f16_f32, RNE
  union { _Float16 h; ushort s; } c; c.h = h; return c.s;
}
__device__ inline f16x2 asf16x2(uint u) {
  union { uint u; f16x2 h; } c; c.u = u; return c.h;
}
__device__ inline uint asuint(f16x2 h) {
  union { f16x2 h; uint u; } c; c.h = h; return c.u;
}

// ---------------- prep: fp32 -> fp16; W diff/had part packed into MFMA
// A-fragment order. Tile (ks 0..79, t 0..1, ob 0..3) = 512 ushorts:
// lane(0..63) = khalf*32 + (o&31) holds W[o][1280 + t*1280 + ks*16 + khalf*8 + 0..7].
__global__ void prep_kernel(const float* __restrict__ feats,
                            const float* __restrict__ W,
                            ushort* __restrict__ fH,
                            ushort* __restrict__ wA,
                            ushort* __restrict__ wP,
                            float* __restrict__ stats,
                            float* __restrict__ Aoi) {
  int idx = blockIdx.x * 256 + threadIdx.x;   // 3200*256 = NFEAT+NWA+NWP
  if (blockIdx.x == 0 && threadIdx.x < 16) stats[threadIdx.x] = 0.0f;
  if (idx < 32768) Aoi[idx] = 0.0f;
  if (idx < NFEAT) {
    fH[idx] = f2h(feats[idx]);
  } else {
    const int e = idx - NFEAT;
    const int o = e / 3840;
    const int c = e - o * 3840;
    const ushort v = f2h(W[e]);
    if (c < 1280) {
      wA[o * 1280 + c] = v;
    } else {
      const int cp = c - 1280;
      const int t = cp / 1280;            // 0=diff, 1=had
      const int kk = cp - t * 1280;
      const int ks = kk >> 4;
      const int khalf = (kk >> 3) & 1;
      const int ko = kk & 7;
      const int lane = khalf * 32 + (o & 31);
      const int tile = (ks * 2 + t) * 4 + (o >> 5);
      wP[tile * 512 + lane * 8 + ko] = v;
    }
  }
}

// ---------------- A[o,i] = sum_c Wa[o,c]*f[i,c] ----------------
// grid 128: 8 i-tiles x 4 kq x 4 ot
__global__ __launch_bounds__(256, 2) void gemma_kernel(
    const ushort* __restrict__ fH, const ushort* __restrict__ wA,
    float* __restrict__ Aoi) {
  __shared__ float red[4][1024];
  const int tid = threadIdx.x, lane = tid & 63, w = tid >> 6;
  const int i0 = (blockIdx.x >> 4) << 5;
  const int kq = (blockIdx.x >> 2) & 3;
  const int ot = blockIdx.x & 3;
  const int rr = lane & 31, half = lane >> 5;
  floatx16 a4;
  #pragma unroll
  for (int r = 0; r < 16; ++r) a4[r] = 0.0f;
  const int kbase = kq * 320 + w * 80 + half * 8;
  #pragma unroll
  for (int ks = 0; ks < 5; ++ks) {
    const int k = kbase + ks * 16;
    U4H8 bf; bf.u = *(const uint4*)(fH + (i0 + rr) * 1280 + k);
    U4H8 af; af.u = *(const uint4*)(wA + (ot * 32 + rr) * 1280 + k);
    a4 = __builtin_amdgcn_mfma_f32_32x32x16_f16(af.h, bf.h, a4, 0, 0, 0);
  }
  #pragma unroll
  for (int r = 0; r < 16; ++r) {
    const int orow = (r & 3) + 8 * (r >> 2) + 4 * half;
    red[w][orow * 32 + rr] = a4[r];
  }
  __syncthreads();
  for (int e = tid; e < 1024; e += 256) {
    float s = red[0][e] + red[1][e] + red[2][e] + red[3][e];
    atomicAdd(&Aoi[(ot * 32 + (e >> 5)) * 256 + i0 + (e & 31)], s);
  }
}

// build diff/had B-fragments: packed f16, no unpack/repack.
__device__ inline void build_pair(const uint4 vj, const uint4 vi, U4H8& d, U4H8& h) {
  const uint ju[4] = {vj.x, vj.y, vj.z, vj.w};
  const uint iu[4] = {vi.x, vi.y, vi.z, vi.w};
  #pragma unroll
  for (int t = 0; t < 4; ++t) {
    f16x2 a = asf16x2(iu[t]);
    f16x2 b = asf16x2(ju[t]);
    f16x2 dd = a - b;
    f16x2 hh = a * b;
    d.w[t] = asuint(dd) & 0x7fff7fffu;   // |a-b| (clear both sign bits)
    h.w[t] = asuint(hh);
  }
}

// ---------------- main fused GEMM: diff+had, K=2560 ----------------
// R13: fat waves. Wave = 2i x 64o x 64j (BOTH j-stripes in-wave):
// 32 MFMA/chunk over 8 acc chains (128 VGPR), 16 loads/chunk (8 W reused
// across 2x the pairs -> bytes/MFMA halved vs R5). Grid 256 = 64 i-quads
// x 4 j-quads, 4 waves/block = (i-pair) x (o-half); 1 block/CU.
// launch_bounds(256,1): VGPR cap 512, no spill. No LDS/barriers in loop.
__global__ __launch_bounds__(256, 1) void gemm_kernel(
    const ushort* __restrict__ fH, const ushort* __restrict__ wP,
    const float* __restrict__ bias, const float* __restrict__ Aoi,
    float* __restrict__ xout, float* __restrict__ stats) {
  __shared__ float sred[16];

  const int tid = threadIdx.x;
  const int blk = blockIdx.x;          // 256 = 64 i-quads * 4 j-quads
  const int lane = tid & 63;
  const int w = tid >> 6;              // 0..3
  const int ip = w >> 1;               // i-pair within quad
  const int ot = w & 1;                // o-half
  const int i0 = (blk >> 2) * 4 + ip * 2;
  const int j0 = (blk & 3) << 6;       // 64 j per block, all in-wave
  const int wo = ot << 6;
  const int rr = lane & 31;
  const int half = lane >> 5;

  // per-lane W-fragment base: o-tiles {2ot, 2ot+1}; lane*8 ushorts
  const ushort* wpl = wP + ((wo >> 5) << 9) + lane * 8;
  const ushort* fi0p = fH + i0 * 1280 + half * 8;
  const ushort* fi1p = fi0p + 1280;
  const ushort* fj0p = fH + (j0 + rr) * 1280 + half * 8;
  const ushort* fj1p = fj0p + 32 * 1280;

  floatx16 acc[2][2][2];   // [i][js][oi]
  #pragma unroll
  for (int a = 0; a < 2; ++a)
    #pragma unroll
    for (int b = 0; b < 2; ++b)
      #pragma unroll
      for (int c = 0; c < 2; ++c)
        #pragma unroll
        for (int r = 0; r < 16; ++r) acc[a][b][c][r] = 0.0f;

  U4H8 wfA[8], wfB[8];
  uint4 vj0A[2], vj1A[2], vi0A[2], vi1A[2];
  uint4 vj0B[2], vj1B[2], vi0B[2], vi1B[2];

  // frag index q = st*4 + t*2 + oi; tile = cc*16 + st*8 + t*4 + oi
#define CHUNK_LOAD(WF, VJ0, VJ1, VI0, VI1, CC) do {                           \
    const int _b = (CC) * 16;                                                 \
    _Pragma("unroll")                                                         \
    for (int _q = 0; _q < 8; ++_q) {                                          \
      const int _st = _q >> 2, _t = (_q >> 1) & 1, _oi = _q & 1;              \
      (WF)[_q].u = *(const uint4*)(wpl + ((_b + _st * 8 + _t * 4 + _oi) << 9)); \
    }                                                                         \
    const int _cb = (CC) << 5;                                                \
    _Pragma("unroll")                                                         \
    for (int _s = 0; _s < 2; ++_s) {                                          \
      (VJ0)[_s] = *(const uint4*)(fj0p + _cb + _s * 16);                      \
      (VJ1)[_s] = *(const uint4*)(fj1p + _cb + _s * 16);                      \
      (VI0)[_s] = *(const uint4*)(fi0p + _cb + _s * 16);                      \
      (VI1)[_s] = *(const uint4*)(fi1p + _cb + _s * 16);                      \
    }                                                                         \
  } while (0)

  // per st: 8 builds (2 js x 2 i), 16 MFMA; per-chain order d-then-h (== R5)
#define CHUNK_COMPUTE(WF, VJ0, VJ1, VI0, VI1) do {                            \
    _Pragma("unroll")                                                         \
    for (int _s = 0; _s < 2; ++_s) {                                          \
      U4H8 d00, h00, d01, h01, d10, h10, d11, h11;                            \
      build_pair((VJ0)[_s], (VI0)[_s], d00, h00);                             \
      build_pair((VJ0)[_s], (VI1)[_s], d01, h01);                             \
      build_pair((VJ1)[_s], (VI0)[_s], d10, h10);                             \
      build_pair((VJ1)[_s], (VI1)[_s], d11, h11);                             \
      _Pragma("unroll")                                                       \
      for (int _oi = 0; _oi < 2; ++_oi) {                                     \
        const f16x8 wd = (WF)[_s * 4 + _oi].h;                                \
        const f16x8 wh = (WF)[_s * 4 + 2 + _oi].h;                            \
        acc[0][0][_oi] = __builtin_amdgcn_mfma_f32_32x32x16_f16(wd, d00.h, acc[0][0][_oi], 0, 0, 0); \
        acc[1][0][_oi] = __builtin_amdgcn_mfma_f32_32x32x16_f16(wd, d01.h, acc[1][0][_oi], 0, 0, 0); \
        acc[0][1][_oi] = __builtin_amdgcn_mfma_f32_32x32x16_f16(wd, d10.h, acc[0][1][_oi], 0, 0, 0); \
        acc[1][1][_oi] = __builtin_amdgcn_mfma_f32_32x32x16_f16(wd, d11.h, acc[1][1][_oi], 0, 0, 0); \
        acc[0][0][_oi] = __builtin_amdgcn_mfma_f32_32x32x16_f16(wh, h00.h, acc[0][0][_oi], 0, 0, 0); \
        acc[1][0][_oi] = __builtin_amdgcn_mfma_f32_32x32x16_f16(wh, h01.h, acc[1][0][_oi], 0, 0, 0); \
        acc[0][1][_oi] = __builtin_amdgcn_mfma_f32_32x32x16_f16(wh, h10.h, acc[0][1][_oi], 0, 0, 0); \
        acc[1][1][_oi] = __builtin_amdgcn_mfma_f32_32x32x16_f16(wh, h11.h, acc[1][1][_oi], 0, 0, 0); \
      }                                                                       \
    }                                                                         \
  } while (0)

  CHUNK_LOAD(wfA, vj0A, vj1A, vi0A, vi1A, 0);
  #pragma unroll 1
  for (int cc = 0; cc < 40; cc += 2) {
    CHUNK_LOAD(wfB, vj0B, vj1B, vi0B, vi1B, cc + 1);   // prefetch odd chunk
    CHUNK_COMPUTE(wfA, vj0A, vj1A, vi0A, vi1A);        // compute even chunk
    if (cc + 2 < 40)
      CHUNK_LOAD(wfA, vj0A, vj1A, vi0A, vi1A, cc + 2); // prefetch next even
    CHUNK_COMPUTE(wfB, vj0B, vj1B, vi0B, vi1B);        // compute odd chunk
  }
#undef CHUNK_LOAD
#undef CHUNK_COMPUTE

  // epilogue: add A[o,i]+A[o,j]+b[o], store, group stats
  float gs[2][2] = {{0.f, 0.f}, {0.f, 0.f}};   // [oi][rg]
  float gq[2][2] = {{0.f, 0.f}, {0.f, 0.f}};
  #pragma unroll
  for (int ii = 0; ii < 2; ++ii) {
    const int irow = i0 + ii;
    #pragma unroll
    for (int js = 0; js < 2; ++js) {
      const int jg = j0 + js * 32 + rr;
      const int mglob = irow * 256 + jg;
      #pragma unroll
      for (int oi = 0; oi < 2; ++oi) {
        #pragma unroll
        for (int r = 0; r < 16; ++r) {
          const int orow = (r & 3) + 8 * (r >> 2) + 4 * half;  // D row map (m74/m101)
          const int o = wo + oi * 32 + orow;
          float x = acc[ii][js][oi][r] + Aoi[o * 256 + irow] + Aoi[o * 256 + jg] + bias[o];
          xout[o * 65536 + mglob] = x;
          gs[oi][r >> 3] += x;
          gq[oi][r >> 3] += x * x;
        }
      }
    }
  }
  if (tid < 16) sred[tid] = 0.0f;
  __syncthreads();
  #pragma unroll
  for (int oi = 0; oi < 2; ++oi) {
    #pragma unroll
    for (int rg = 0; rg < 2; ++rg) {
      float s = gs[oi][rg], qv = gq[oi][rg];
      for (int off = 32; off > 0; off >>= 1) {
        s += __shfl_xor(s, off, 64);
        qv += __shfl_xor(qv, off, 64);
      }
      if (lane == 0) {
        const int g = (wo >> 4) + oi * 2 + rg;
        atomicAdd(&sred[g], s);
        atomicAdd(&sred[8 + g], qv);
      }
    }
  }
  __syncthreads();
  if (tid < 16) atomicAdd(&stats[tid], sred[tid]);
}

// ---------------- groupnorm + exact gelu, in place ----------------
__global__ void norm_kernel(float* __restrict__ xout,
                            const float* __restrict__ stats,
                            const float* __restrict__ gamma,
                            const float* __restrict__ beta) {
  const int idx = blockIdx.x * 256 + threadIdx.x;
  const int e = idx << 2;
  const int o = e >> 16;
  const int g = o >> 4;
  const float invN = 1.0f / 1048576.0f;  // 16*65536 per group
  const float mean = stats[g] * invN;
  const float var = stats[8 + g] * invN - mean * mean;
  const float inv = rsqrtf(var + 1e-5f);
  const float ga = gamma[o], be = beta[o];
  float4 v = *(float4*)(xout + e);
  float* pv = &v.x;
  #pragma unroll
  for (int t = 0; t < 4; ++t) {
    float xn = (pv[t] - mean) * inv * ga + be;
    pv[t] = 0.5f * xn * (1.0f + erff(xn * 0.70710678118654752f));
  }
  *(float4*)(xout + e) = v;
}

extern "C" void kernel_launch(void* const* d_in, const int* in_sizes, int n_in,
                              void* d_out, int out_size, void* d_ws, size_t ws_size,
                              hipStream_t stream) {
  const float* feats = (const float*)d_in[0];
  const float* W     = (const float*)d_in[1];
  const float* bias  = (const float*)d_in[2];
  const float* gamma = (const float*)d_in[3];
  const float* beta  = (const float*)d_in[4];
  float* out = (float*)d_out;

  ushort* fH = (ushort*)d_ws;
  ushort* wA = fH + NFEAT;
  ushort* wP = wA + NWA;
  float* stats = (float*)(wP + NWP);
  float* Aoi = stats + 16;

  prep_kernel<<<3200, 256, 0, stream>>>(feats, W, fH, wA, wP, stats, Aoi);
  gemma_kernel<<<128, 256, 0, stream>>>(fH, wA, Aoi);
  gemm_kernel<<<256, 256, 0, stream>>>(fH, wP, bias, Aoi, out, stats);
  norm_kernel<<<8192, 256, 0, stream>>>(out, stats, gamma, beta);
}